// Round 8
// baseline (421.816 us; speedup 1.0000x reference)
//
#include <hip/hip_runtime.h>

#define LSEQ 1024

typedef __attribute__((ext_vector_type(8))) short bf16x8;
typedef __attribute__((ext_vector_type(4))) float f32x4;

__device__ __forceinline__ float gelu_f(float x){
    return 0.5f*x*(1.0f+erff(x*0.7071067811865476f));
}

__device__ __forceinline__ unsigned f2bf1(float x){
    unsigned u = __float_as_uint(x);
    return (u + 0x7fffu + ((u>>16)&1u)) >> 16;
}
__device__ __forceinline__ unsigned packbf(float lo, float hi){
    return f2bf1(lo) | (f2bf1(hi)<<16);
}

// ---------------------------------------------------------------------------
// MFMA GEMM v3: C[n] = A (M,K) x transform(B[n]) (K,1024).
// Tile = 64 m x 32 l -> grid (32, M/64, 8) = 1024-2048 blocks = 4-8 blocks/CU
// (v2 was 512 blocks = 2/CU, grid-starved at 18% occupancy). y/z strides stay
// = 0 mod 8 so same-B-tile blocks share an XCD (L2 reuse preserved).
// transform = optional groupnorm + affine + optional residual + optional gelu.
// Register-prefetch of next K-chunk; accumulates per-sample sum/sumsq.
// ---------------------------------------------------------------------------
__global__ __launch_bounds__(256,2) void gemm_mfma(
    const float* __restrict__ A,
    const float* __restrict__ B,
    const float* __restrict__ Bres,
    float* __restrict__ C,
    const float* __restrict__ in_stats,
    const float* __restrict__ gw,
    const float* __restrict__ gb,
    float in_cnt_inv, int apply_gelu,
    int M, int K,
    float* __restrict__ out_stats)
{
    __shared__ short As[64*40];   // [m][k] stride 40
    __shared__ short Bs[32*40];   // [l][k] stride 40

    int tid = threadIdx.x;
    int n  = blockIdx.z;
    int n0 = blockIdx.x*32;       // l offset (32-wide strip)
    int m0 = blockIdx.y*64;       // output-channel offset
    int wave = tid>>6, lane = tid&63;
    int col = lane&15, quad = lane>>4;

    float mu=0.f, istd=1.f;
    if (in_stats){
        float s1 = in_stats[2*n], s2 = in_stats[2*n+1];
        mu = s1*in_cnt_inv;
        float var = s2*in_cnt_inv - mu*mu;
        istd = rsqrtf(var + 1e-5f);
    }

    const float* Bn = B + (size_t)n*K*LSEQ;
    const float* Rn = Bres ? (Bres + (size_t)n*K*LSEQ) : nullptr;

    int sm = tid>>2,  sk = (tid&3)*8;   // A: row sm (0..63), k sk..sk+7
    int sl = tid&31,  scg = tid>>5;     // B: col sl (0..31), channels scg*4..+3

    f32x4 acc[2];
    acc[0] = (f32x4){0.f,0.f,0.f,0.f};
    acc[1] = (f32x4){0.f,0.f,0.f,0.f};

    const float* ap = A + (size_t)(m0+sm)*K + sk;

    // ---- preload chunk 0 ----
    float4 a0 = *(const float4*)(ap);
    float4 a1 = *(const float4*)(ap+4);
    float bv[4], rv[4];
    #pragma unroll
    for(int cc=0;cc<4;cc++){
        int c = scg*4 + cc;
        bv[cc] = Bn[(size_t)c*LSEQ + n0 + sl];
        if(Rn) rv[cc] = Rn[(size_t)c*LSEQ + n0 + sl];
    }

    for(int k0=0; k0<K; k0+=32){
        // pack A
        uint4 pa;
        pa.x = packbf(a0.x,a0.y); pa.y = packbf(a0.z,a0.w);
        pa.z = packbf(a1.x,a1.y); pa.w = packbf(a1.z,a1.w);
        // transform + pack B
        uint2 pb;
        {
            float tv[4];
            #pragma unroll
            for(int cc=0;cc<4;cc++){
                int c = k0 + scg*4 + cc;
                float w_=1.f, b_=0.f;
                if (gw){ w_=gw[c]; b_=gb[c]; }
                float t = (bv[cc]-mu)*istd*w_ + b_;
                if (Rn) t += rv[cc];
                if (apply_gelu) t = gelu_f(t);
                tv[cc]=t;
            }
            pb.x = packbf(tv[0],tv[1]); pb.y = packbf(tv[2],tv[3]);
        }
        __syncthreads();   // prior-iter LDS consumers done
        *(uint4*)&As[sm*40 + sk] = pa;
        *(uint2*)&Bs[sl*40 + scg*4] = pb;
        __syncthreads();

        // prefetch next chunk (retires behind the MFMAs)
        if(k0+32 < K){
            a0 = *(const float4*)(ap + k0+32);
            a1 = *(const float4*)(ap + k0+36);
            #pragma unroll
            for(int cc=0;cc<4;cc++){
                int c = k0+32 + scg*4 + cc;
                bv[cc] = Bn[(size_t)c*LSEQ + n0 + sl];
                if(Rn) rv[cc] = Rn[(size_t)c*LSEQ + n0 + sl];
            }
        }

        // wave = m-tile; two 16-col l-tiles
        bf16x8 af = *(bf16x8*)&As[(wave*16+col)*40 + quad*8];
        #pragma unroll
        for(int t=0;t<2;t++){
            bf16x8 bf = *(bf16x8*)&Bs[(t*16+col)*40 + quad*8];
            acc[t] = __builtin_amdgcn_mfma_f32_16x16x32_bf16(af, bf, acc[t], 0,0,0);
        }
    }

    __syncthreads();
    size_t cbase = (size_t)n*M*LSEQ;
    float lsum=0.f, lsq=0.f;
    #pragma unroll
    for(int t=0;t<2;t++){
        #pragma unroll
        for(int r=0;r<4;r++){
            int m = m0 + wave*16 + quad*4 + r;
            int l = n0 + t*16 + col;
            float v = acc[t][r];
            C[cbase + (size_t)m*LSEQ + l] = v;
            lsum += v; lsq += v*v;
        }
    }
    float* scr = (float*)As;
    scr[tid] = lsum; scr[256+tid] = lsq;
    __syncthreads();
    for(int s=128;s>0;s>>=1){
        if(tid<s){ scr[tid]+=scr[tid+s]; scr[256+tid]+=scr[256+tid+s]; }
        __syncthreads();
    }
    if(tid==0){
        atomicAdd(&out_stats[2*n],   scr[0]);
        atomicAdd(&out_stats[2*n+1], scr[256]);
    }
}

// ---------------------------------------------------------------------------
// head_cov: per (head, 128-pos chunk) partial 16x16 covariances of normalized
// q and k, plus per-channel sums. S2 of the LxL logit map = tr(Mk.Mq).
// ---------------------------------------------------------------------------
__global__ __launch_bounds__(256,2) void head_cov(
    const float* __restrict__ qkv,
    const float* __restrict__ s_qkv,
    const float* __restrict__ gq_w, const float* __restrict__ gq_b,
    float* __restrict__ covq, float* __restrict__ covk,
    float* __restrict__ sumq, float* __restrict__ sumk)
{
    __shared__ float Kq[16*132];
    __shared__ float Kk[16*132];
    int b = blockIdx.x;
    int head = b>>3, chunk = b&7;
    int n = head>>3, h = head&7;
    int tid = threadIdx.x;
    int m0 = chunk*128;

    float s1 = s_qkv[2*n], s2v = s_qkv[2*n+1];
    float mu  = s1*(1.f/524288.f);
    float var = s2v*(1.f/524288.f) - mu*mu;
    float istd = rsqrtf(var + 1e-5f);

    const float* base = qkv + (size_t)n*512*LSEQ;
    int m = tid&127, cg = tid>>7;
    #pragma unroll
    for(int cc=0;cc<8;cc++){
        int c = cg*8+cc;
        int chq = h*16+c, chk = 128+h*16+c;
        Kq[c*132+m] = (base[(size_t)chq*LSEQ+m0+m]-mu)*istd*gq_w[chq]+gq_b[chq];
        Kk[c*132+m] = (base[(size_t)chk*LSEQ+m0+m]-mu)*istd*gq_w[chk]+gq_b[chk];
    }
    __syncthreads();

    int i = tid>>4, j = tid&15;
    float q0=0,q1=0,q2=0,q3=0, k0=0,k1=0,k2=0,k3=0;
    for(int mm=0;mm<128;mm+=4){
        float4 qa = *(const float4*)&Kq[i*132+mm];
        float4 qb = *(const float4*)&Kq[j*132+mm];
        q0 += qa.x*qb.x; q1 += qa.y*qb.y; q2 += qa.z*qb.z; q3 += qa.w*qb.w;
        float4 ka = *(const float4*)&Kk[i*132+mm];
        float4 kb = *(const float4*)&Kk[j*132+mm];
        k0 += ka.x*kb.x; k1 += ka.y*kb.y; k2 += ka.z*kb.z; k3 += ka.w*kb.w;
    }
    atomicAdd(&covq[head*256 + i*16 + j], (q0+q1)+(q2+q3));
    atomicAdd(&covk[head*256 + i*16 + j], (k0+k1)+(k2+k3));

    if(i==0){
        float s=0.f;
        for(int mm=0;mm<128;mm+=4){
            float4 v = *(const float4*)&Kq[j*132+mm];
            s += (v.x+v.y)+(v.z+v.w);
        }
        atomicAdd(&sumq[head*16+j], s);
    }
    if(i==1){
        float s=0.f;
        for(int mm=0;mm<128;mm+=4){
            float4 v = *(const float4*)&Kk[j*132+mm];
            s += (v.x+v.y)+(v.z+v.w);
        }
        atomicAdd(&sumk[head*16+j], s);
    }
}

// ---------------------------------------------------------------------------
// head_fin: istd of the LxL logit map per head from the covariances.
// ---------------------------------------------------------------------------
__global__ __launch_bounds__(256) void head_fin(
    const float* __restrict__ covq, const float* __restrict__ covk,
    const float* __restrict__ sumq, const float* __restrict__ sumk,
    float* __restrict__ istd_head)
{
    int tid = threadIdx.x;
    int head = tid>>2, part = tid&3;
    double S2 = 0.0;
    #pragma unroll 8
    for(int e=part*64; e<part*64+64; e++)
        S2 += (double)covq[head*256+e]*(double)covk[head*256+e];
    S2 += __shfl_xor(S2,1);
    S2 += __shfl_xor(S2,2);
    if(part==0){
        double S1 = 0.0;
        for(int c=0;c<16;c++) S1 += (double)sumq[head*16+c]*(double)sumk[head*16+c];
        double cnt = 1048576.0;
        double mean = S1/cnt;
        double v2 = S2/cnt - mean*mean;
        if(v2 < 0.0) v2 = 0.0;
        istd_head[head] = (float)(1.0/sqrt(v2 + 1e-5));
    }
}

// ---------------------------------------------------------------------------
// Attention v5: MFMA flash attention, XCD-swizzled grid. head = b&63 so the
// 8 row-blocks of a head share b mod 8 -> same XCD -> K/V L2-resident
// (8 heads x 196KB = 1.6MB per 4MB XCD L2). v4's head = b>>3 spread them
// across all XCDs -> 65MB HBM fetch (the kernel's whole 64us).
// ---------------------------------------------------------------------------
__global__ __launch_bounds__(256) void attn_kernel(
    const float* __restrict__ qkv,
    const float* __restrict__ s_qkv,
    const float* __restrict__ gq_w, const float* __restrict__ gq_b,
    const float* __restrict__ istd_head,
    float* __restrict__ out,
    float* __restrict__ out_stats)
{
    __shared__ short Qs[128*40];    // [row][c], c 0..15 real, 16..31 zero
    __shared__ short Ks[128*40];    // [m][c],   same padding
    __shared__ short Vs[32*136];    // [d][m]
    __shared__ short Ps[128*152];   // [row][m] bf16 P
    __shared__ float bounds_l[128];
    __shared__ float issum_l[128];
    __shared__ float sred4[4];

    int b = blockIdx.x;
    int head = b&63, rb = b>>6;     // XCD swizzle (was head=b>>3, rb=b&7)
    int n = head>>3, h = head&7;
    int tid = threadIdx.x;
    int wv = tid>>6, lane = tid&63;
    int col = lane&15, quad = lane>>4;
    int l0 = rb*128;

    const float* base = qkv + (size_t)n*512*LSEQ;
    float s1 = s_qkv[2*n], s2v = s_qkv[2*n+1];
    float mu  = s1*(1.f/524288.f);
    float var = s2v*(1.f/524288.f) - mu*mu;
    float istd = rsqrtf(var + 1e-5f);
    float ih = istd_head[head];

    {
        int row = tid>>1, hf = tid&1;
        uint4 z = {0,0,0,0};
        *(uint4*)&Qs[row*40 + 16 + hf*8] = z;
        *(uint4*)&Ks[row*40 + 16 + hf*8] = z;
    }

    {
        int row = tid>>1, cg = tid&1;
        float qn2p = 0.f;
        float qv[8];
        #pragma unroll
        for(int cc=0;cc<8;cc++){
            int ch = h*16 + cg*8 + cc;
            float w_ = gq_w[ch]*istd, b_ = gq_b[ch]-mu*istd*gq_w[ch];
            float x = base[(size_t)ch*LSEQ + l0 + row];
            float v = x*w_ + b_;
            qv[cc] = v;
            qn2p += v*v;
        }
        uint4 pq;
        pq.x = packbf(qv[0],qv[1]); pq.y = packbf(qv[2],qv[3]);
        pq.z = packbf(qv[4],qv[5]); pq.w = packbf(qv[6],qv[7]);
        *(uint4*)&Qs[row*40 + cg*8] = pq;
        float oth = __shfl_xor(qn2p, 1);
        if(cg==0) bounds_l[row] = sqrtf(qn2p + oth);
    }

    {
        float kn2max = 0.f;
        #pragma unroll
        for(int j=0;j<4;j++){
            int m = tid + j*256;
            float s = 0.f;
            for(int c=0;c<16;c++){
                int ch = 128+h*16+c;
                float x = base[(size_t)ch*LSEQ + m];
                float kv = (x-mu)*istd*gq_w[ch]+gq_b[ch];
                s += kv*kv;
            }
            kn2max = fmaxf(kn2max, s);
        }
        #pragma unroll
        for(int d=1;d<64;d<<=1) kn2max = fmaxf(kn2max, __shfl_xor(kn2max,d));
        if(lane==0) sred4[wv] = kn2max;
    }
    __syncthreads();
    float kmax = sqrtf(fmaxf(fmaxf(sred4[0],sred4[1]),fmaxf(sred4[2],sred4[3])));

    bf16x8 qf[2];
    float B2[2]; int grow[2];
    #pragma unroll
    for(int t=0;t<2;t++){
        int rl = (2*wv+t)*16 + col;
        qf[t] = *(bf16x8*)&Qs[rl*40 + quad*8];
        B2[t] = bounds_l[rl]*kmax*ih;
        grow[t] = l0 + rl;
    }

    int km_l = tid>>1, kg = tid&1;
    float kw8[8], kb8[8];
    #pragma unroll
    for(int cc=0;cc<8;cc++){
        int ch = 128+h*16+kg*8+cc;
        kw8[cc] = gq_w[ch]*istd;
        kb8[cc] = gq_b[ch]-mu*istd*gq_w[ch];
    }
    int vd = tid>>3, vmg = tid&7;
    float vw, vb;
    {
        int ch = 256+h*32+vd;
        vw = gq_w[ch]*istd;
        vb = gq_b[ch]-mu*istd*gq_w[ch];
    }
    const float* kp = base + (size_t)(128+h*16+kg*8)*LSEQ + km_l;
    const float* vp = base + (size_t)(256+h*32+vd)*LSEQ + vmg*16;

    f32x4 acc[2][2];
    #pragma unroll
    for(int t=0;t<2;t++){ acc[t][0]=(f32x4){0,0,0,0}; acc[t][1]=(f32x4){0,0,0,0}; }
    float ssum[2] = {0.f,0.f};
    const f32x4 zero4 = {0.f,0.f,0.f,0.f};

    for(int mc=0;mc<8;mc++){
        int M0 = mc*128;
        {
            float kv[8];
            #pragma unroll
            for(int cc=0;cc<8;cc++)
                kv[cc] = kp[(size_t)cc*LSEQ + M0]*kw8[cc] + kb8[cc];
            uint4 pk;
            pk.x=packbf(kv[0],kv[1]); pk.y=packbf(kv[2],kv[3]);
            pk.z=packbf(kv[4],kv[5]); pk.w=packbf(kv[6],kv[7]);
            *(uint4*)&Ks[km_l*40 + kg*8] = pk;
        }
        {
            float4 x0 = *(const float4*)&vp[M0];
            float4 x1 = *(const float4*)&vp[M0+4];
            float4 x2 = *(const float4*)&vp[M0+8];
            float4 x3 = *(const float4*)&vp[M0+12];
            uint4 p0, p1;
            p0.x = packbf(x0.x*vw+vb, x0.y*vw+vb);
            p0.y = packbf(x0.z*vw+vb, x0.w*vw+vb);
            p0.z = packbf(x1.x*vw+vb, x1.y*vw+vb);
            p0.w = packbf(x1.z*vw+vb, x1.w*vw+vb);
            p1.x = packbf(x2.x*vw+vb, x2.y*vw+vb);
            p1.y = packbf(x2.z*vw+vb, x2.w*vw+vb);
            p1.z = packbf(x3.x*vw+vb, x3.y*vw+vb);
            p1.w = packbf(x3.z*vw+vb, x3.w*vw+vb);
            *(uint4*)&Vs[vd*136 + vmg*16]     = p0;
            *(uint4*)&Vs[vd*136 + vmg*16 + 8] = p1;
        }
        __syncthreads();

        #pragma unroll
        for(int mt=0;mt<8;mt++){
            bf16x8 ak = *(bf16x8*)&Ks[(mt*16+col)*40 + quad*8];
            #pragma unroll
            for(int t=0;t<2;t++){
                f32x4 sc = __builtin_amdgcn_mfma_f32_16x16x32_bf16(ak, qf[t], zero4, 0,0,0);
                int mbase = M0 + mt*16 + quad*4;
                float pr[4];
                #pragma unroll
                for(int r=0;r<4;r++){
                    float e = __expf(fmaf(sc[r], ih, -B2[t]));
                    pr[r] = (mbase + r == grow[t]) ? 0.f : e;
                    ssum[t] += pr[r];
                }
                uint2 pw;
                pw.x = packbf(pr[0],pr[1]); pw.y = packbf(pr[2],pr[3]);
                *(uint2*)&Ps[((2*wv+t)*16+col)*152 + mt*16 + quad*4] = pw;
            }
        }
        #pragma unroll
        for(int kk=0;kk<4;kk++){
            bf16x8 bv0 = *(bf16x8*)&Vs[( col)*136 + kk*32 + quad*8];
            bf16x8 bv1 = *(bf16x8*)&Vs[((16+col))*136 + kk*32 + quad*8];
            #pragma unroll
            for(int t=0;t<2;t++){
                bf16x8 ap = *(bf16x8*)&Ps[((2*wv+t)*16+col)*152 + kk*32 + quad*8];
                acc[t][0] = __builtin_amdgcn_mfma_f32_16x16x32_bf16(ap, bv0, acc[t][0], 0,0,0);
                acc[t][1] = __builtin_amdgcn_mfma_f32_16x16x32_bf16(ap, bv1, acc[t][1], 0,0,0);
            }
        }
        __syncthreads();
    }

    #pragma unroll
    for(int t=0;t<2;t++){
        float v = ssum[t];
        v += __shfl_xor(v,16);
        v += __shfl_xor(v,32);
        if(quad==0) issum_l[(2*wv+t)*16+col] = v;
    }
    __syncthreads();
    if(tid<128) issum_l[tid] = 1.f/issum_l[tid];
    __syncthreads();

    float* ep = (float*)Ps;
    #pragma unroll
    for(int t=0;t<2;t++)
        #pragma unroll
        for(int dt=0;dt<2;dt++)
            *(f32x4*)&ep[(dt*16+col)*132 + (2*wv+t)*16 + quad*4] = acc[t][dt];
    __syncthreads();

    float lsum=0.f, lsq=0.f;
    size_t obase = (size_t)n*262144 + (size_t)h*32*LSEQ + l0;
    #pragma unroll
    for(int t=0;t<16;t++){
        int idx = t*256 + tid;
        int d = idx>>7, row = idx&127;
        float y = ep[d*132+row]*issum_l[row];
        out[obase + (size_t)d*LSEQ + row] = y;
        lsum += y; lsq += y*y;
    }
    float* red = (float*)Ks;
    red[tid]=lsum; red[256+tid]=lsq;
    __syncthreads();
    for(int s=128;s>0;s>>=1){
        if(tid<s){ red[tid]+=red[tid+s]; red[256+tid]+=red[256+tid+s]; }
        __syncthreads();
    }
    if(tid==0){
        atomicAdd(&out_stats[2*n],   red[0]);
        atomicAdd(&out_stats[2*n+1], red[256]);
    }
}

// ---------------------------------------------------------------------------
// ew_final: out = gelu( f1 + gn_g2(h2) ) with f1 = gelu( f + gn_go(x) )
// recomputed on the fly (f1 never materialized).
// ---------------------------------------------------------------------------
__global__ __launch_bounds__(256) void ew_final(
    const float* __restrict__ f, const float* __restrict__ x,
    const float* __restrict__ h2,
    const float* __restrict__ sx, const float* __restrict__ sh,
    const float* __restrict__ go_w, const float* __restrict__ go_b,
    const float* __restrict__ g2_w, const float* __restrict__ g2_b,
    float* __restrict__ out)
{
    int idx = blockIdx.x*256 + threadIdx.x;   // float4 index
    int n = idx >> 16;
    int c = (idx >> 8) & 255;
    float mux, isx, muh, ish;
    {
        float s1 = sx[2*n], s2 = sx[2*n+1];
        mux = s1*(1.f/262144.f);
        isx = rsqrtf(s2*(1.f/262144.f) - mux*mux + 1e-5f);
        float t1 = sh[2*n], t2 = sh[2*n+1];
        muh = t1*(1.f/262144.f);
        ish = rsqrtf(t2*(1.f/262144.f) - muh*muh + 1e-5f);
    }
    float wo = go_w[c]*isx, bo = go_b[c]-mux*isx*go_w[c];
    float w2 = g2_w[c]*ish, b2 = g2_b[c]-muh*ish*g2_w[c];
    float4 xv = ((const float4*)x)[idx];
    float4 fv = ((const float4*)f)[idx];
    float4 hv = ((const float4*)h2)[idx];
    float4 ov;
    float f1;
    f1 = gelu_f(fv.x + xv.x*wo+bo); ov.x = gelu_f(f1 + hv.x*w2+b2);
    f1 = gelu_f(fv.y + xv.y*wo+bo); ov.y = gelu_f(f1 + hv.y*w2+b2);
    f1 = gelu_f(fv.z + xv.z*wo+bo); ov.z = gelu_f(f1 + hv.z*w2+b2);
    f1 = gelu_f(fv.w + xv.w*wo+bo); ov.w = gelu_f(f1 + hv.w*w2+b2);
    ((float4*)out)[idx] = ov;
}

// ---------------------------------------------------------------------------
extern "C" void kernel_launch(void* const* d_in, const int* in_sizes, int n_in,
                              void* d_out, int out_size, void* d_ws, size_t ws_size,
                              hipStream_t stream) {
    const float* f     = (const float*)d_in[0];
    const float* w_z   = (const float*)d_in[1];
    const float* gz_w  = (const float*)d_in[2];
    const float* gz_b  = (const float*)d_in[3];
    const float* w_qkv = (const float*)d_in[4];
    const float* gq_w  = (const float*)d_in[5];
    const float* gq_b  = (const float*)d_in[6];
    const float* w_out = (const float*)d_in[7];
    const float* go_w  = (const float*)d_in[8];
    const float* go_b  = (const float*)d_in[9];
    const float* w_f1  = (const float*)d_in[10];
    const float* g1_w  = (const float*)d_in[11];
    const float* g1_b  = (const float*)d_in[12];
    const float* w_f2  = (const float*)d_in[13];
    const float* g2_w  = (const float*)d_in[14];
    const float* g2_b  = (const float*)d_in[15];

    float* ws = (float*)d_ws;
    float* stats = ws;                 // 256 floats
    float* s_z    = stats + 0;
    float* s_qkv  = stats + 16;
    float* s_attn = stats + 32;
    float* s_x    = stats + 48;
    float* s_h1   = stats + 64;
    float* s_h2   = stats + 80;
    float* istdh  = stats + 96;        // 64
    const size_t SM = (size_t)256*1024;
    float* buf0 = ws + 256;            // 8*SM  : z0 -> attn_out -> h2
    float* buf1 = buf0 + 8*SM;         // 16*SM : qkv -> h1
    float* buf2 = buf1 + 16*SM;        // 8*SM  : covs (pre-attn) -> x (persists)
    float* outp = (float*)d_out;

    float* covq = buf2;                // 64*256
    float* covk = buf2 + 16384;        // 64*256
    float* sumq = buf2 + 32768;        // 64*16
    float* sumk = buf2 + 33792;        // 64*16

    hipMemsetAsync(stats, 0, 256*sizeof(float), stream);
    hipMemsetAsync(covq, 0, 34816*sizeof(float), stream);

    dim3 blk(256);
    // z0 = w_z @ gelu(f)
    gemm_mfma<<<dim3(32,4,8),blk,0,stream>>>(w_z, f, nullptr, buf0,
        nullptr, nullptr, nullptr, 0.f, 1, 256, 256, s_z);
    // qkv = w_qkv @ gelu(gn(z0))
    gemm_mfma<<<dim3(32,8,8),blk,0,stream>>>(w_qkv, buf0, nullptr, buf1,
        s_z, gz_w, gz_b, 1.f/262144.f, 1, 512, 256, s_qkv);
    // per-head covariances + analytic logit-LN istd
    head_cov<<<512,blk,0,stream>>>(buf1, s_qkv, gq_w, gq_b, covq, covk, sumq, sumk);
    head_fin<<<1,blk,0,stream>>>(covq, covk, sumq, sumk, istdh);
    // attention -> attn_out (overwrites z0)
    attn_kernel<<<512,blk,0,stream>>>(buf1, s_qkv, gq_w, gq_b, istdh, buf0, s_attn);
    // x = w_out @ gelu(ln(attn_out))   (overwrites cov scratch)
    gemm_mfma<<<dim3(32,4,8),blk,0,stream>>>(w_out, buf0, nullptr, buf2,
        s_attn, nullptr, nullptr, 1.f/262144.f, 1, 256, 256, s_x);
    // h1 = w_ffn1 @ gelu(f + gn_go(x))   (ew fused into B-transform)
    gemm_mfma<<<dim3(32,8,8),blk,0,stream>>>(w_f1, buf2, f, buf1,
        s_x, go_w, go_b, 1.f/262144.f, 1, 512, 256, s_h1);
    // h2 = w_ffn2 @ gelu(gn_g1(h1))
    gemm_mfma<<<dim3(32,4,8),blk,0,stream>>>(w_f2, buf1, nullptr, buf0,
        s_h1, g1_w, g1_b, 1.f/524288.f, 1, 256, 512, s_h2);
    // out = gelu( gelu(f + gn_go(x)) + gn_g2(h2) )
    ew_final<<<2048,blk,0,stream>>>(f, buf2, buf0, s_x, s_h2,
        go_w, go_b, g2_w, g2_b, outp);
}

// Round 9
// 320.306 us; speedup vs baseline: 1.3169x; 1.3169x over previous
//
#include <hip/hip_runtime.h>

#define LSEQ 1024

typedef __attribute__((ext_vector_type(8))) short bf16x8;
typedef __attribute__((ext_vector_type(4))) float f32x4;

__device__ __forceinline__ float gelu_f(float x){
    return 0.5f*x*(1.0f+erff(x*0.7071067811865476f));
}

__device__ __forceinline__ unsigned f2bf1(float x){
    unsigned u = __float_as_uint(x);
    return (u + 0x7fffu + ((u>>16)&1u)) >> 16;
}
__device__ __forceinline__ unsigned packbf(float lo, float hi){
    return f2bf1(lo) | (f2bf1(hi)<<16);
}

// ---------------------------------------------------------------------------
// pack_weights: all 5 weight matrices fp32 -> bf16 [m][k] contiguous.
// Segments (float4 units): w_z 16384 | w_qkv 32768 | w_out 16384 |
// w_f1 32768 | w_f2 32768  (cum 16384,49152,65536,98304,131072)
// ---------------------------------------------------------------------------
__global__ __launch_bounds__(256) void pack_weights(
    const float* __restrict__ w0, const float* __restrict__ w1,
    const float* __restrict__ w2, const float* __restrict__ w3,
    const float* __restrict__ w4, unsigned short* __restrict__ dst)
{
    int idx4 = blockIdx.x*256 + threadIdx.x;
    const float* src; int off4;
    if(idx4 < 16384){ src=w0; off4=idx4; }
    else if(idx4 < 49152){ src=w1; off4=idx4-16384; }
    else if(idx4 < 65536){ src=w2; off4=idx4-49152; }
    else if(idx4 < 98304){ src=w3; off4=idx4-65536; }
    else { src=w4; off4=idx4-98304; }
    float4 v = ((const float4*)src)[off4];
    uint2 p; p.x = packbf(v.x,v.y); p.y = packbf(v.z,v.w);
    ((uint2*)dst)[idx4] = p;
}

// ---------------------------------------------------------------------------
// xform_bf16: dst[l][c] (bf16, l-major) = gelu( (src[c][l]-mu)*istd*gw+gb
//                                               [+ res[c][l]] )
// once per element (GEMM no longer redundantly re-transforms). LDS-tiled
// 64c x 64l transpose; coalesced on both sides.
// grid (16, C/64, 8)
// ---------------------------------------------------------------------------
__global__ __launch_bounds__(256,2) void xform_bf16(
    const float* __restrict__ src, const float* __restrict__ res,
    const float* __restrict__ stats,
    const float* __restrict__ gw, const float* __restrict__ gb,
    float cnt_inv, int C, unsigned short* __restrict__ dst)
{
    __shared__ float T[64][68];
    int n = blockIdx.z;
    int ltile = blockIdx.x*64, ctile = blockIdx.y*64;
    int tid = threadIdx.x;

    float mu=0.f, istd=1.f;
    if(stats){
        float s1 = stats[2*n], s2 = stats[2*n+1];
        mu = s1*cnt_inv;
        istd = rsqrtf(s2*cnt_inv - mu*mu + 1e-5f);
    }
    const float* s = src + (size_t)n*C*LSEQ;
    const float* r = res ? res + (size_t)n*C*LSEQ : nullptr;

    int cl = tid>>4, l4 = (tid&15)*4;
    #pragma unroll
    for(int p=0;p<4;p++){
        int c_loc = p*16 + cl;
        int c = ctile + c_loc;
        float w_ = 1.f, b_ = 0.f;
        if(stats){ w_ = istd; b_ = -mu*istd; }
        if(gw){ b_ = gb[c] + b_*gw[c]; w_ *= gw[c]; }
        float4 v = *(const float4*)&s[(size_t)c*LSEQ + ltile + l4];
        float4 t;
        t.x = v.x*w_+b_; t.y = v.y*w_+b_; t.z = v.z*w_+b_; t.w = v.w*w_+b_;
        if(r){
            float4 rv = *(const float4*)&r[(size_t)c*LSEQ + ltile + l4];
            t.x += rv.x; t.y += rv.y; t.z += rv.z; t.w += rv.w;
        }
        t.x = gelu_f(t.x); t.y = gelu_f(t.y); t.z = gelu_f(t.z); t.w = gelu_f(t.w);
        *(float4*)&T[c_loc][l4] = t;
    }
    __syncthreads();

    int l_loc = tid>>2, cg = (tid&3)*16;
    uint4 o0, o1;
    o0.x = packbf(T[cg+0][l_loc],  T[cg+1][l_loc]);
    o0.y = packbf(T[cg+2][l_loc],  T[cg+3][l_loc]);
    o0.z = packbf(T[cg+4][l_loc],  T[cg+5][l_loc]);
    o0.w = packbf(T[cg+6][l_loc],  T[cg+7][l_loc]);
    o1.x = packbf(T[cg+8][l_loc],  T[cg+9][l_loc]);
    o1.y = packbf(T[cg+10][l_loc], T[cg+11][l_loc]);
    o1.z = packbf(T[cg+12][l_loc], T[cg+13][l_loc]);
    o1.w = packbf(T[cg+14][l_loc], T[cg+15][l_loc]);
    unsigned short* d = dst + (size_t)n*LSEQ*C + (size_t)(ltile+l_loc)*C + ctile + cg;
    *(uint4*)d = o0;
    *(uint4*)(d+8) = o1;
}

// ---------------------------------------------------------------------------
// gemm_bf16: C[n] = Abf (M,K bf16 [m][k]) x Bbf (K,1024 bf16 [l][k] l-major).
// Pure data movement + MFMA: per chunk/thread 2 dwordx4 loads, 2 b128 LDS
// writes, 5 frag reads, 4 MFMAs, ~20 VALU (no transform - see xform_bf16).
// 64x64 tile; grid (16, M/64, 8). fp32 C out + per-sample sum/sumsq stats.
// ---------------------------------------------------------------------------
__global__ __launch_bounds__(256,2) void gemm_bf16(
    const unsigned short* __restrict__ Abf,
    const unsigned short* __restrict__ Bbf,
    float* __restrict__ C,
    int M, int K,
    float* __restrict__ out_stats)
{
    __shared__ short As[64*40];   // [m][k] pad 40
    __shared__ short Bs[64*40];   // [l][k] pad 40

    int tid = threadIdx.x;
    int n = blockIdx.z, n0 = blockIdx.x*64, m0 = blockIdx.y*64;
    int wave = tid>>6, lane = tid&63;
    int col = lane&15, quad = lane>>4;
    int sr = tid>>2, sk = (tid&3)*8;

    const unsigned short* apt = Abf + (size_t)(m0+sr)*K + sk;
    const unsigned short* bpt = Bbf + ((size_t)n*LSEQ + n0+sr)*K + sk;

    f32x4 acc[4];
    #pragma unroll
    for(int t=0;t<4;t++) acc[t] = (f32x4){0.f,0.f,0.f,0.f};

    uint4 a = *(const uint4*)apt;
    uint4 b = *(const uint4*)bpt;

    for(int k0=0; k0<K; k0+=32){
        __syncthreads();
        *(uint4*)&As[sr*40 + sk] = a;
        *(uint4*)&Bs[sr*40 + sk] = b;
        __syncthreads();
        if(k0+32 < K){
            a = *(const uint4*)(apt + k0+32);
            b = *(const uint4*)(bpt + k0+32);
        }
        bf16x8 af = *(bf16x8*)&As[(wave*16+col)*40 + quad*8];
        #pragma unroll
        for(int t=0;t<4;t++){
            bf16x8 bf = *(bf16x8*)&Bs[(t*16+col)*40 + quad*8];
            acc[t] = __builtin_amdgcn_mfma_f32_16x16x32_bf16(af, bf, acc[t], 0,0,0);
        }
    }

    __syncthreads();
    size_t cbase = (size_t)n*M*LSEQ;
    float lsum=0.f, lsq=0.f;
    #pragma unroll
    for(int t=0;t<4;t++){
        #pragma unroll
        for(int r2=0;r2<4;r2++){
            int m = m0 + wave*16 + quad*4 + r2;
            int l = n0 + t*16 + col;
            float v = acc[t][r2];
            C[cbase + (size_t)m*LSEQ + l] = v;
            lsum += v; lsq += v*v;
        }
    }
    float* scr = (float*)As;
    scr[tid] = lsum; scr[256+tid] = lsq;
    __syncthreads();
    for(int s=128;s>0;s>>=1){
        if(tid<s){ scr[tid]+=scr[tid+s]; scr[256+tid]+=scr[256+tid+s]; }
        __syncthreads();
    }
    if(tid==0){
        atomicAdd(&out_stats[2*n],   scr[0]);
        atomicAdd(&out_stats[2*n+1], scr[256]);
    }
}

// ---------------------------------------------------------------------------
// head_cov / head_fin: analytic logit-LN istd via tr(Mk.Mq) (unchanged).
// ---------------------------------------------------------------------------
__global__ __launch_bounds__(256,2) void head_cov(
    const float* __restrict__ qkv,
    const float* __restrict__ s_qkv,
    const float* __restrict__ gq_w, const float* __restrict__ gq_b,
    float* __restrict__ covq, float* __restrict__ covk,
    float* __restrict__ sumq, float* __restrict__ sumk)
{
    __shared__ float Kq[16*132];
    __shared__ float Kk[16*132];
    int b = blockIdx.x;
    int head = b>>3, chunk = b&7;
    int n = head>>3, h = head&7;
    int tid = threadIdx.x;
    int m0 = chunk*128;

    float s1 = s_qkv[2*n], s2v = s_qkv[2*n+1];
    float mu  = s1*(1.f/524288.f);
    float var = s2v*(1.f/524288.f) - mu*mu;
    float istd = rsqrtf(var + 1e-5f);

    const float* base = qkv + (size_t)n*512*LSEQ;
    int m = tid&127, cg = tid>>7;
    #pragma unroll
    for(int cc=0;cc<8;cc++){
        int c = cg*8+cc;
        int chq = h*16+c, chk = 128+h*16+c;
        Kq[c*132+m] = (base[(size_t)chq*LSEQ+m0+m]-mu)*istd*gq_w[chq]+gq_b[chq];
        Kk[c*132+m] = (base[(size_t)chk*LSEQ+m0+m]-mu)*istd*gq_w[chk]+gq_b[chk];
    }
    __syncthreads();

    int i = tid>>4, j = tid&15;
    float q0=0,q1=0,q2=0,q3=0, k0=0,k1=0,k2=0,k3=0;
    for(int mm=0;mm<128;mm+=4){
        float4 qa = *(const float4*)&Kq[i*132+mm];
        float4 qb = *(const float4*)&Kq[j*132+mm];
        q0 += qa.x*qb.x; q1 += qa.y*qb.y; q2 += qa.z*qb.z; q3 += qa.w*qb.w;
        float4 ka = *(const float4*)&Kk[i*132+mm];
        float4 kb = *(const float4*)&Kk[j*132+mm];
        k0 += ka.x*kb.x; k1 += ka.y*kb.y; k2 += ka.z*kb.z; k3 += ka.w*kb.w;
    }
    atomicAdd(&covq[head*256 + i*16 + j], (q0+q1)+(q2+q3));
    atomicAdd(&covk[head*256 + i*16 + j], (k0+k1)+(k2+k3));

    if(i==0){
        float s=0.f;
        for(int mm=0;mm<128;mm+=4){
            float4 v = *(const float4*)&Kq[j*132+mm];
            s += (v.x+v.y)+(v.z+v.w);
        }
        atomicAdd(&sumq[head*16+j], s);
    }
    if(i==1){
        float s=0.f;
        for(int mm=0;mm<128;mm+=4){
            float4 v = *(const float4*)&Kk[j*132+mm];
            s += (v.x+v.y)+(v.z+v.w);
        }
        atomicAdd(&sumk[head*16+j], s);
    }
}

__global__ __launch_bounds__(256) void head_fin(
    const float* __restrict__ covq, const float* __restrict__ covk,
    const float* __restrict__ sumq, const float* __restrict__ sumk,
    float* __restrict__ istd_head)
{
    int tid = threadIdx.x;
    int head = tid>>2, part = tid&3;
    double S2 = 0.0;
    #pragma unroll 8
    for(int e=part*64; e<part*64+64; e++)
        S2 += (double)covq[head*256+e]*(double)covk[head*256+e];
    S2 += __shfl_xor(S2,1);
    S2 += __shfl_xor(S2,2);
    if(part==0){
        double S1 = 0.0;
        for(int c=0;c<16;c++) S1 += (double)sumq[head*16+c]*(double)sumk[head*16+c];
        double cnt = 1048576.0;
        double mean = S1/cnt;
        double v2 = S2/cnt - mean*mean;
        if(v2 < 0.0) v2 = 0.0;
        istd_head[head] = (float)(1.0/sqrt(v2 + 1e-5));
    }
}

// ---------------------------------------------------------------------------
// Attention v5 (unchanged): MFMA flash attention, XCD-swizzled grid.
// ---------------------------------------------------------------------------
__global__ __launch_bounds__(256) void attn_kernel(
    const float* __restrict__ qkv,
    const float* __restrict__ s_qkv,
    const float* __restrict__ gq_w, const float* __restrict__ gq_b,
    const float* __restrict__ istd_head,
    float* __restrict__ out,
    float* __restrict__ out_stats)
{
    __shared__ short Qs[128*40];
    __shared__ short Ks[128*40];
    __shared__ short Vs[32*136];
    __shared__ short Ps[128*152];
    __shared__ float bounds_l[128];
    __shared__ float issum_l[128];
    __shared__ float sred4[4];

    int b = blockIdx.x;
    int head = b&63, rb = b>>6;     // XCD swizzle
    int n = head>>3, h = head&7;
    int tid = threadIdx.x;
    int wv = tid>>6, lane = tid&63;
    int col = lane&15, quad = lane>>4;
    int l0 = rb*128;

    const float* base = qkv + (size_t)n*512*LSEQ;
    float s1 = s_qkv[2*n], s2v = s_qkv[2*n+1];
    float mu  = s1*(1.f/524288.f);
    float var = s2v*(1.f/524288.f) - mu*mu;
    float istd = rsqrtf(var + 1e-5f);
    float ih = istd_head[head];

    {
        int row = tid>>1, hf = tid&1;
        uint4 z = {0,0,0,0};
        *(uint4*)&Qs[row*40 + 16 + hf*8] = z;
        *(uint4*)&Ks[row*40 + 16 + hf*8] = z;
    }

    {
        int row = tid>>1, cg = tid&1;
        float qn2p = 0.f;
        float qv[8];
        #pragma unroll
        for(int cc=0;cc<8;cc++){
            int ch = h*16 + cg*8 + cc;
            float w_ = gq_w[ch]*istd, b_ = gq_b[ch]-mu*istd*gq_w[ch];
            float x = base[(size_t)ch*LSEQ + l0 + row];
            float v = x*w_ + b_;
            qv[cc] = v;
            qn2p += v*v;
        }
        uint4 pq;
        pq.x = packbf(qv[0],qv[1]); pq.y = packbf(qv[2],qv[3]);
        pq.z = packbf(qv[4],qv[5]); pq.w = packbf(qv[6],qv[7]);
        *(uint4*)&Qs[row*40 + cg*8] = pq;
        float oth = __shfl_xor(qn2p, 1);
        if(cg==0) bounds_l[row] = sqrtf(qn2p + oth);
    }

    {
        float kn2max = 0.f;
        #pragma unroll
        for(int j=0;j<4;j++){
            int m = tid + j*256;
            float s = 0.f;
            for(int c=0;c<16;c++){
                int ch = 128+h*16+c;
                float x = base[(size_t)ch*LSEQ + m];
                float kv = (x-mu)*istd*gq_w[ch]+gq_b[ch];
                s += kv*kv;
            }
            kn2max = fmaxf(kn2max, s);
        }
        #pragma unroll
        for(int d=1;d<64;d<<=1) kn2max = fmaxf(kn2max, __shfl_xor(kn2max,d));
        if(lane==0) sred4[wv] = kn2max;
    }
    __syncthreads();
    float kmax = sqrtf(fmaxf(fmaxf(sred4[0],sred4[1]),fmaxf(sred4[2],sred4[3])));

    bf16x8 qf[2];
    float B2[2]; int grow[2];
    #pragma unroll
    for(int t=0;t<2;t++){
        int rl = (2*wv+t)*16 + col;
        qf[t] = *(bf16x8*)&Qs[rl*40 + quad*8];
        B2[t] = bounds_l[rl]*kmax*ih;
        grow[t] = l0 + rl;
    }

    int km_l = tid>>1, kg = tid&1;
    float kw8[8], kb8[8];
    #pragma unroll
    for(int cc=0;cc<8;cc++){
        int ch = 128+h*16+kg*8+cc;
        kw8[cc] = gq_w[ch]*istd;
        kb8[cc] = gq_b[ch]-mu*istd*gq_w[ch];
    }
    int vd = tid>>3, vmg = tid&7;
    float vw, vb;
    {
        int ch = 256+h*32+vd;
        vw = gq_w[ch]*istd;
        vb = gq_b[ch]-mu*istd*gq_w[ch];
    }
    const float* kp = base + (size_t)(128+h*16+kg*8)*LSEQ + km_l;
    const float* vp = base + (size_t)(256+h*32+vd)*LSEQ + vmg*16;

    f32x4 acc[2][2];
    #pragma unroll
    for(int t=0;t<2;t++){ acc[t][0]=(f32x4){0,0,0,0}; acc[t][1]=(f32x4){0,0,0,0}; }
    float ssum[2] = {0.f,0.f};
    const f32x4 zero4 = {0.f,0.f,0.f,0.f};

    for(int mc=0;mc<8;mc++){
        int M0 = mc*128;
        {
            float kv[8];
            #pragma unroll
            for(int cc=0;cc<8;cc++)
                kv[cc] = kp[(size_t)cc*LSEQ + M0]*kw8[cc] + kb8[cc];
            uint4 pk;
            pk.x=packbf(kv[0],kv[1]); pk.y=packbf(kv[2],kv[3]);
            pk.z=packbf(kv[4],kv[5]); pk.w=packbf(kv[6],kv[7]);
            *(uint4*)&Ks[km_l*40 + kg*8] = pk;
        }
        {
            float4 x0 = *(const float4*)&vp[M0];
            float4 x1 = *(const float4*)&vp[M0+4];
            float4 x2 = *(const float4*)&vp[M0+8];
            float4 x3 = *(const float4*)&vp[M0+12];
            uint4 p0, p1;
            p0.x = packbf(x0.x*vw+vb, x0.y*vw+vb);
            p0.y = packbf(x0.z*vw+vb, x0.w*vw+vb);
            p0.z = packbf(x1.x*vw+vb, x1.y*vw+vb);
            p0.w = packbf(x1.z*vw+vb, x1.w*vw+vb);
            p1.x = packbf(x2.x*vw+vb, x2.y*vw+vb);
            p1.y = packbf(x2.z*vw+vb, x2.w*vw+vb);
            p1.z = packbf(x3.x*vw+vb, x3.y*vw+vb);
            p1.w = packbf(x3.z*vw+vb, x3.w*vw+vb);
            *(uint4*)&Vs[vd*136 + vmg*16]     = p0;
            *(uint4*)&Vs[vd*136 + vmg*16 + 8] = p1;
        }
        __syncthreads();

        #pragma unroll
        for(int mt=0;mt<8;mt++){
            bf16x8 ak = *(bf16x8*)&Ks[(mt*16+col)*40 + quad*8];
            #pragma unroll
            for(int t=0;t<2;t++){
                f32x4 sc = __builtin_amdgcn_mfma_f32_16x16x32_bf16(ak, qf[t], zero4, 0,0,0);
                int mbase = M0 + mt*16 + quad*4;
                float pr[4];
                #pragma unroll
                for(int r=0;r<4;r++){
                    float e = __expf(fmaf(sc[r], ih, -B2[t]));
                    pr[r] = (mbase + r == grow[t]) ? 0.f : e;
                    ssum[t] += pr[r];
                }
                uint2 pw;
                pw.x = packbf(pr[0],pr[1]); pw.y = packbf(pr[2],pr[3]);
                *(uint2*)&Ps[((2*wv+t)*16+col)*152 + mt*16 + quad*4] = pw;
            }
        }
        #pragma unroll
        for(int kk=0;kk<4;kk++){
            bf16x8 bv0 = *(bf16x8*)&Vs[( col)*136 + kk*32 + quad*8];
            bf16x8 bv1 = *(bf16x8*)&Vs[((16+col))*136 + kk*32 + quad*8];
            #pragma unroll
            for(int t=0;t<2;t++){
                bf16x8 ap = *(bf16x8*)&Ps[((2*wv+t)*16+col)*152 + kk*32 + quad*8];
                acc[t][0] = __builtin_amdgcn_mfma_f32_16x16x32_bf16(ap, bv0, acc[t][0], 0,0,0);
                acc[t][1] = __builtin_amdgcn_mfma_f32_16x16x32_bf16(ap, bv1, acc[t][1], 0,0,0);
            }
        }
        __syncthreads();
    }

    #pragma unroll
    for(int t=0;t<2;t++){
        float v = ssum[t];
        v += __shfl_xor(v,16);
        v += __shfl_xor(v,32);
        if(quad==0) issum_l[(2*wv+t)*16+col] = v;
    }
    __syncthreads();
    if(tid<128) issum_l[tid] = 1.f/issum_l[tid];
    __syncthreads();

    float* ep = (float*)Ps;
    #pragma unroll
    for(int t=0;t<2;t++)
        #pragma unroll
        for(int dt=0;dt<2;dt++)
            *(f32x4*)&ep[(dt*16+col)*132 + (2*wv+t)*16 + quad*4] = acc[t][dt];
    __syncthreads();

    float lsum=0.f, lsq=0.f;
    size_t obase = (size_t)n*262144 + (size_t)h*32*LSEQ + l0;
    #pragma unroll
    for(int t=0;t<16;t++){
        int idx = t*256 + tid;
        int d = idx>>7, row = idx&127;
        float y = ep[d*132+row]*issum_l[row];
        out[obase + (size_t)d*LSEQ + row] = y;
        lsum += y; lsq += y*y;
    }
    float* red = (float*)Ks;
    red[tid]=lsum; red[256+tid]=lsq;
    __syncthreads();
    for(int s=128;s>0;s>>=1){
        if(tid<s){ red[tid]+=red[tid+s]; red[256+tid]+=red[256+tid+s]; }
        __syncthreads();
    }
    if(tid==0){
        atomicAdd(&out_stats[2*n],   red[0]);
        atomicAdd(&out_stats[2*n+1], red[256]);
    }
}

// ---------------------------------------------------------------------------
// ew_final: out = gelu( f1 + gn_g2(h2) ), f1 = gelu(f + gn_go(x)) recomputed.
// ---------------------------------------------------------------------------
__global__ __launch_bounds__(256) void ew_final(
    const float* __restrict__ f, const float* __restrict__ x,
    const float* __restrict__ h2,
    const float* __restrict__ sx, const float* __restrict__ sh,
    const float* __restrict__ go_w, const float* __restrict__ go_b,
    const float* __restrict__ g2_w, const float* __restrict__ g2_b,
    float* __restrict__ out)
{
    int idx = blockIdx.x*256 + threadIdx.x;
    int n = idx >> 16;
    int c = (idx >> 8) & 255;
    float mux, isx, muh, ish;
    {
        float s1 = sx[2*n], s2 = sx[2*n+1];
        mux = s1*(1.f/262144.f);
        isx = rsqrtf(s2*(1.f/262144.f) - mux*mux + 1e-5f);
        float t1 = sh[2*n], t2 = sh[2*n+1];
        muh = t1*(1.f/262144.f);
        ish = rsqrtf(t2*(1.f/262144.f) - muh*muh + 1e-5f);
    }
    float wo = go_w[c]*isx, bo = go_b[c]-mux*isx*go_w[c];
    float w2 = g2_w[c]*ish, b2 = g2_b[c]-muh*ish*g2_w[c];
    float4 xv = ((const float4*)x)[idx];
    float4 fv = ((const float4*)f)[idx];
    float4 hv = ((const float4*)h2)[idx];
    float4 ov;
    float f1;
    f1 = gelu_f(fv.x + xv.x*wo+bo); ov.x = gelu_f(f1 + hv.x*w2+b2);
    f1 = gelu_f(fv.y + xv.y*wo+bo); ov.y = gelu_f(f1 + hv.y*w2+b2);
    f1 = gelu_f(fv.z + xv.z*wo+bo); ov.z = gelu_f(f1 + hv.z*w2+b2);
    f1 = gelu_f(fv.w + xv.w*wo+bo); ov.w = gelu_f(f1 + hv.w*w2+b2);
    ((float4*)out)[idx] = ov;
}

// ---------------------------------------------------------------------------
extern "C" void kernel_launch(void* const* d_in, const int* in_sizes, int n_in,
                              void* d_out, int out_size, void* d_ws, size_t ws_size,
                              hipStream_t stream) {
    const float* f     = (const float*)d_in[0];
    const float* w_z   = (const float*)d_in[1];
    const float* gz_w  = (const float*)d_in[2];
    const float* gz_b  = (const float*)d_in[3];
    const float* w_qkv = (const float*)d_in[4];
    const float* gq_w  = (const float*)d_in[5];
    const float* gq_b  = (const float*)d_in[6];
    const float* w_out = (const float*)d_in[7];
    const float* go_w  = (const float*)d_in[8];
    const float* go_b  = (const float*)d_in[9];
    const float* w_f1  = (const float*)d_in[10];
    const float* g1_w  = (const float*)d_in[11];
    const float* g1_b  = (const float*)d_in[12];
    const float* w_f2  = (const float*)d_in[13];
    const float* g2_w  = (const float*)d_in[14];
    const float* g2_b  = (const float*)d_in[15];

    float* ws = (float*)d_ws;
    float* stats = ws;                 // 256 floats
    float* s_z    = stats + 0;
    float* s_qkv  = stats + 16;
    float* s_attn = stats + 32;
    float* s_x    = stats + 48;
    float* s_h1   = stats + 64;
    float* s_h2   = stats + 80;
    float* istdh  = stats + 96;

    // fp32 regions
    float* qkvF = ws + 256;            // 4M floats: qkv -> h1 -> h2
    float* z0F  = qkvF + 4194304;      // 2M floats: z0 -> attn_out -> t4(bf16)
    float* xF   = z0F + 2097152;       // 2M floats: covs -> x (persists)
    // bf16 regions
    unsigned short* t0 = (unsigned short*)(xF + 2097152);  // 2M us: t0 -> t2
    unsigned short* t1 = t0 + 2097152;                     // 2M us: t1 -> t3
    unsigned short* wp = t1 + 2097152;                     // 512K us
    unsigned short* t4 = (unsigned short*)z0F;             // 4M us (8MB region)
    unsigned short* wp_z   = wp;
    unsigned short* wp_qkv = wp + 65536;
    unsigned short* wp_out = wp + 196608;
    unsigned short* wp_f1  = wp + 262144;
    unsigned short* wp_f2  = wp + 393216;

    float* covq = xF;                  // 64*256
    float* covk = xF + 16384;
    float* sumq = xF + 32768;
    float* sumk = xF + 33792;

    float* outp = (float*)d_out;

    hipMemsetAsync(stats, 0, 256*sizeof(float), stream);
    hipMemsetAsync(covq, 0, 34816*sizeof(float), stream);

    dim3 blk(256);
    // weights -> bf16
    pack_weights<<<512,blk,0,stream>>>(w_z, w_qkv, w_out, w_f1, w_f2, wp);
    // t0 = bf16[gelu(f)]  (l-major)
    xform_bf16<<<dim3(16,4,8),blk,0,stream>>>(f, nullptr, nullptr, nullptr, nullptr,
        0.f, 256, t0);
    // z0 = w_z @ t0
    gemm_bf16<<<dim3(16,4,8),blk,0,stream>>>(wp_z, t0, z0F, 256, 256, s_z);
    // t1 = bf16[gelu(gn_gz(z0))]
    xform_bf16<<<dim3(16,4,8),blk,0,stream>>>(z0F, nullptr, s_z, gz_w, gz_b,
        1.f/262144.f, 256, t1);
    // qkv = w_qkv @ t1
    gemm_bf16<<<dim3(16,8,8),blk,0,stream>>>(wp_qkv, t1, qkvF, 512, 256, s_qkv);
    // analytic logit-LN istd
    head_cov<<<512,blk,0,stream>>>(qkvF, s_qkv, gq_w, gq_b, covq, covk, sumq, sumk);
    head_fin<<<1,blk,0,stream>>>(covq, covk, sumq, sumk, istdh);
    // attention -> attn_out (z0F region)
    attn_kernel<<<512,blk,0,stream>>>(qkvF, s_qkv, gq_w, gq_b, istdh, z0F, s_attn);
    // t2 = bf16[gelu(ln(attn_out))]   (t2 aliases t0)
    xform_bf16<<<dim3(16,4,8),blk,0,stream>>>(z0F, nullptr, s_attn, nullptr, nullptr,
        1.f/262144.f, 256, t0);
    // x = w_out @ t2   (overwrites cov scratch)
    gemm_bf16<<<dim3(16,4,8),blk,0,stream>>>(wp_out, t0, xF, 256, 256, s_x);
    // t3 = bf16[gelu(f + gn_go(x))]   (t3 aliases t1)
    xform_bf16<<<dim3(16,4,8),blk,0,stream>>>(xF, f, s_x, go_w, go_b,
        1.f/262144.f, 256, t1);
    // h1 = w_f1 @ t3  (h1 -> qkvF region; qkv dead after attn)
    gemm_bf16<<<dim3(16,8,8),blk,0,stream>>>(wp_f1, t1, qkvF, 512, 256, s_h1);
    // t4 = bf16[gelu(gn_g1(h1))]   (t4 -> z0F region; attn_out dead)
    xform_bf16<<<dim3(16,8,8),blk,0,stream>>>(qkvF, nullptr, s_h1, g1_w, g1_b,
        1.f/524288.f, 512, t4);
    // h2 = w_f2 @ t4  (h2 -> qkvF region; h1 dead)
    gemm_bf16<<<dim3(16,4,8),blk,0,stream>>>(wp_f2, t4, qkvF, 256, 512, s_h2);
    // out = gelu( gelu(f + gn_go(x)) + gn_g2(h2) )
    ew_final<<<2048,blk,0,stream>>>(f, xF, qkvF, s_x, s_h2,
        go_w, go_b, g2_w, g2_b, outp);
}